// Round 1
// 577.406 us; speedup vs baseline: 1.0046x; 1.0046x over previous
//
#include <hip/hip_runtime.h>
#include <stdint.h>

typedef __attribute__((ext_vector_type(8))) short short8;
typedef __attribute__((ext_vector_type(4))) float floatx4;

#define TLEN 2048
#define BATCH 4
#define EMB 2048
#define NHEADS 16
#define HDIM 128
#define MROWS (BATCH * TLEN) /* 8192 */
#define QTILES (TLEN / 64)   /* 32 */

__device__ __forceinline__ ushort f2bf(float f) {
    union { float f; uint32_t u; } v; v.f = f;
    uint32_t u = v.u;
    return (ushort)((u + 0x7fffu + ((u >> 16) & 1u)) >> 16);
}

__device__ __forceinline__ void async_copy16(const ushort* g, ushort* l) {
    __builtin_amdgcn_global_load_lds(
        (const __attribute__((address_space(1))) uint32_t*)g,
        (__attribute__((address_space(3))) uint32_t*)l, 16, 0, 0);
}

// ---------------- cast fp32 -> bf16 ----------------
__global__ __launch_bounds__(256) void cast_bf16_kernel(const float* __restrict__ in,
                                                        ushort* __restrict__ out, int n) {
    int i = (blockIdx.x * 256 + threadIdx.x) * 4;
    if (i >= n) return;
    float4 f = *(const float4*)(in + i);
    ushort4 o;
    o.x = f2bf(f.x); o.y = f2bf(f.y); o.z = f2bf(f.z); o.w = f2bf(f.w);
    *(ushort4*)(out + i) = o;
}

// ---------------- transpose + cast: fp32 [R][Cc] -> bf16 [Cc][R] ----------------
__global__ void transpose_cast_kernel(const float* __restrict__ in, ushort* __restrict__ out,
                                      int R, int Cc) {
    __shared__ float tile[32][33];
    int x = blockIdx.x * 32 + threadIdx.x;
    int y0 = blockIdx.y * 32;
#pragma unroll
    for (int i = 0; i < 4; i++) {
        int y = y0 + threadIdx.y + i * 8;
        tile[threadIdx.y + i * 8][threadIdx.x] = in[(size_t)y * Cc + x];
    }
    __syncthreads();
    int xo = y0 + threadIdx.x;
#pragma unroll
    for (int i = 0; i < 4; i++) {
        int yo = blockIdx.x * 32 + threadIdx.y + i * 8;
        out[(size_t)yo * R + xo] = f2bf(tile[threadIdx.x][threadIdx.y + i * 8]);
    }
}

// ---------------- bf16 MFMA GEMM (m97 structure): C = A[M,K] * Bt[N,K]^T ----------------
// 128x128 tile, BK=64, global_load_lds width-16 staging, unpadded LDS.
// MODE 0: bf16 out. MODE 1: fp32 out + bias. MODE 2: KV split (K normal / V transposed-packed).
template <int MODE>
__global__ __launch_bounds__(256) void gemm_bt_kernel(const ushort* __restrict__ A,
                                                      const ushort* __restrict__ Bt,
                                                      void* __restrict__ Cp,
                                                      void* __restrict__ Cp2,
                                                      const float* __restrict__ bias,
                                                      int M, int N, int K) {
    __shared__ ushort As[128 * 64];
    __shared__ ushort Bs[128 * 64];
    int tid = threadIdx.x;
    int wid = tid >> 6, lane = tid & 63;
    int quad = lane >> 4, l15 = lane & 15;
    int m0 = blockIdx.y * 128;
    int n0 = blockIdx.x * 128;
    int rm = (wid >> 1) * 64;
    int cn = (wid & 1) * 64;
    int grow = lane >> 3;       // 0..7
    int gcol = (lane & 7) * 8;  // 0..56

    floatx4 acc[4][4];
#pragma unroll
    for (int i = 0; i < 4; i++)
#pragma unroll
        for (int j = 0; j < 4; j++)
#pragma unroll
            for (int r = 0; r < 4; r++) acc[i][j][r] = 0.f;

    for (int kk = 0; kk < K; kk += 64) {
#pragma unroll
        for (int c = 0; c < 4; c++) {
            int chunk = wid * 4 + c;              // 0..15, wave-uniform
            int row = chunk * 8 + grow;
            async_copy16(A + (size_t)(m0 + row) * K + kk + gcol, &As[chunk * 512]);
            async_copy16(Bt + (size_t)(n0 + row) * K + kk + gcol, &Bs[chunk * 512]);
        }
        __syncthreads();
#pragma unroll
        for (int ks = 0; ks < 64; ks += 32) {
            short8 af[4], bf[4];
#pragma unroll
            for (int i = 0; i < 4; i++)
                af[i] = *(const short8*)(&As[(rm + i * 16 + l15) * 64 + ks + quad * 8]);
#pragma unroll
            for (int j = 0; j < 4; j++)
                bf[j] = *(const short8*)(&Bs[(cn + j * 16 + l15) * 64 + ks + quad * 8]);
#pragma unroll
            for (int i = 0; i < 4; i++)
#pragma unroll
                for (int j = 0; j < 4; j++)
                    acc[i][j] = __builtin_amdgcn_mfma_f32_16x16x32_bf16(af[i], bf[j], acc[i][j], 0, 0, 0);
        }
        __syncthreads();
    }
#pragma unroll
    for (int i = 0; i < 4; i++)
#pragma unroll
        for (int j = 0; j < 4; j++) {
            if (MODE == 2 && n0 != 0) {
                int d = cn + j * 16 + l15;
                int row = m0 + rm + i * 16 + quad * 4;
                ushort4 o;
                o.x = f2bf(acc[i][j][0]); o.y = f2bf(acc[i][j][1]);
                o.z = f2bf(acc[i][j][2]); o.w = f2bf(acc[i][j][3]);
                *(ushort4*)((ushort*)Cp2 + (size_t)d * M + row) = o;
            } else {
#pragma unroll
                for (int r = 0; r < 4; r++) {
                    int row = m0 + rm + i * 16 + quad * 4 + r;
                    int col = n0 + cn + j * 16 + l15;
                    float v = acc[i][j][r];
                    if (MODE == 0) {
                        ((ushort*)Cp)[(size_t)row * N + col] = f2bf(v);
                    } else if (MODE == 1) {
                        ((float*)Cp)[(size_t)row * N + col] = v + bias[col];
                    } else {
                        ((ushort*)Cp)[(size_t)row * HDIM + col] = f2bf(v);
                    }
                }
            }
        }
}

// ---------------- flash MQA attention: paired q-tiles, 2 heads, fixed-max softmax ----------------
// grid: (QTILES/2, H/2, B). Block processes q-tiles {x, 31-x} -> 33 iterations uniformly.
// SWAPPED QK^T: compute S^T = mfma(K_frag, Q_frag) so each lane holds 4 CONSECUTIVE KEYS
// (quad*4+r) of one q-row (l15). P then packs into ushort4 -> one ds_write_b64 per (hh,j)
// instead of 32 scalar ds_write_b16 (which were ~all of the 9.7M bank-conflict cycles:
// 4-way conflicted scatter). PV reads of Ps are unchanged ([qrow][key] layout preserved).
__global__ __launch_bounds__(256, 2) void mqa_attn_kernel(const ushort* __restrict__ Qb,
                                                          const ushort* __restrict__ Kb,
                                                          const ushort* __restrict__ Vg,
                                                          ushort* __restrict__ Ab) {
    __shared__ ushort Ks[64][136];      // [key][d] 128+8
    __shared__ ushort Vs[128][72];      // V^T [d][key] 64+8
    __shared__ ushort Ps[4][2][16][72]; // per-wave, per-head P [16 q][64 key]
    int tid = threadIdx.x;
    int wid = tid >> 6, lane = tid & 63;
    int quad = lane >> 4, l15 = lane & 15;
    int h0 = blockIdx.y * 2, b = blockIdx.z;
    const float scale2 = 0.08838834764831845f * 1.4426950408889634f; // 1/sqrt(128)*log2(e)
    const ushort* kbase0 = Kb + (size_t)b * TLEN * HDIM;
    const ushort* vbase0 = Vg + (size_t)b * TLEN;

#pragma unroll 1
    for (int t = 0; t < 2; t++) {
        int qt = (t == 0) ? blockIdx.x : (QTILES - 1 - blockIdx.x);
        size_t qrowbase = (size_t)b * TLEN + qt * 64;

        short8 aq[2][4];
#pragma unroll
        for (int hh = 0; hh < 2; hh++) {
            const ushort* qp = Qb + (qrowbase + wid * 16 + l15) * EMB + (h0 + hh) * HDIM + quad * 8;
#pragma unroll
            for (int kd = 0; kd < 4; kd++) aq[hh][kd] = *(const short8*)(qp + kd * 32);
        }

        float lsum[2];
        floatx4 o_acc[2][8];
#pragma unroll
        for (int hh = 0; hh < 2; hh++) {
            lsum[hh] = 0.f;
#pragma unroll
            for (int nd = 0; nd < 8; nd++)
#pragma unroll
                for (int r = 0; r < 4; r++) o_acc[hh][nd][r] = 0.f;
        }

        // prefetch tile 0 into registers
        uint4 kreg[4], vreg[4];
#pragma unroll
        for (int it = 0; it < 4; it++) {
            int idx = tid + it * 256;
            kreg[it] = *(const uint4*)(kbase0 + (size_t)(idx >> 4) * HDIM + (idx & 15) * 8);
            vreg[it] = *(const uint4*)(vbase0 + (size_t)(idx >> 3) * MROWS + (idx & 7) * 8);
        }

#pragma unroll 1
        for (int jt = 0; jt <= qt; ++jt) {
            // registers -> LDS
#pragma unroll
            for (int it = 0; it < 4; it++) {
                int idx = tid + it * 256;
                *(uint4*)(&Ks[idx >> 4][(idx & 15) * 8]) = kreg[it];
                *(uint4*)(&Vs[idx >> 3][(idx & 7) * 8]) = vreg[it];
            }
            __syncthreads();
            // prefetch next tile (overlaps compute below)
            if (jt < qt) {
                const ushort* kb = kbase0 + (size_t)(jt + 1) * 64 * HDIM;
                const ushort* vb = vbase0 + (jt + 1) * 64;
#pragma unroll
                for (int it = 0; it < 4; it++) {
                    int idx = tid + it * 256;
                    kreg[it] = *(const uint4*)(kb + (size_t)(idx >> 4) * HDIM + (idx & 15) * 8);
                    vreg[it] = *(const uint4*)(vb + (size_t)(idx >> 3) * MROWS + (idx & 7) * 8);
                }
            }

            // S^T = K Q^T for both heads (swapped operands), shared A-fragments.
            // Lane (l15, quad): sacc[hh][j][r] = S[key = j*16+quad*4+r][qrow = l15]
            floatx4 sacc[2][4];
#pragma unroll
            for (int hh = 0; hh < 2; hh++)
#pragma unroll
                for (int j = 0; j < 4; j++)
#pragma unroll
                    for (int r = 0; r < 4; r++) sacc[hh][j][r] = 0.f;
            __builtin_amdgcn_s_setprio(1);
#pragma unroll
            for (int kd = 0; kd < 4; kd++)
#pragma unroll
                for (int j = 0; j < 4; j++) {
                    short8 ak = *(const short8*)(&Ks[j * 16 + l15][kd * 32 + quad * 8]);
                    sacc[0][j] = __builtin_amdgcn_mfma_f32_16x16x32_bf16(ak, aq[0][kd], sacc[0][j], 0, 0, 0);
                    sacc[1][j] = __builtin_amdgcn_mfma_f32_16x16x32_bf16(ak, aq[1][kd], sacc[1][j], 0, 0, 0);
                }
            __builtin_amdgcn_s_setprio(0);

            // fixed-max softmax: e = exp2(s*scale2); key-contiguous per lane -> packed b64 store
            int rowloc = wid * 16 + l15;  // this lane's q-row within the 64-row tile
            bool diag = (jt == qt);
#pragma unroll
            for (int hh = 0; hh < 2; hh++) {
#pragma unroll
                for (int j = 0; j < 4; j++) {
                    float e[4];
#pragma unroll
                    for (int r = 0; r < 4; r++) {
                        float ev = exp2f(sacc[hh][j][r] * scale2);
                        if (diag && (j * 16 + quad * 4 + r) > rowloc) ev = 0.f;
                        e[r] = ev;
                        lsum[hh] += ev;
                    }
                    ushort4 pk;
                    pk.x = f2bf(e[0]); pk.y = f2bf(e[1]);
                    pk.z = f2bf(e[2]); pk.w = f2bf(e[3]);
                    *(ushort4*)(&Ps[wid][hh][l15][j * 16 + quad * 4]) = pk;
                }
            }

            // O += P V, shared V fragments
            __builtin_amdgcn_s_setprio(1);
#pragma unroll
            for (int kt = 0; kt < 2; kt++) {
                short8 pf0 = *(const short8*)(&Ps[wid][0][l15][kt * 32 + quad * 8]);
                short8 pf1 = *(const short8*)(&Ps[wid][1][l15][kt * 32 + quad * 8]);
#pragma unroll
                for (int nd = 0; nd < 8; nd++) {
                    short8 vf = *(const short8*)(&Vs[nd * 16 + l15][kt * 32 + quad * 8]);
                    o_acc[0][nd] = __builtin_amdgcn_mfma_f32_16x16x32_bf16(pf0, vf, o_acc[0][nd], 0, 0, 0);
                    o_acc[1][nd] = __builtin_amdgcn_mfma_f32_16x16x32_bf16(pf1, vf, o_acc[1][nd], 0, 0, 0);
                }
            }
            __builtin_amdgcn_s_setprio(0);
            __syncthreads();
        }

        // row sums: lane holds partial for q-row l15; reduce across quads, then gather
        // the 4 rows (quad*4+r) this lane's o_acc covers via width-16 shfl.
#pragma unroll
        for (int hh = 0; hh < 2; hh++) {
            float ls = lsum[hh];
            ls += __shfl_xor(ls, 16);
            ls += __shfl_xor(ls, 32);
            float inv_l[4];
#pragma unroll
            for (int r = 0; r < 4; r++) inv_l[r] = 1.f / __shfl(ls, quad * 4 + r, 16);
#pragma unroll
            for (int nd = 0; nd < 8; nd++)
#pragma unroll
                for (int r = 0; r < 4; r++) {
                    size_t row = qrowbase + wid * 16 + quad * 4 + r;
                    int col = (h0 + hh) * HDIM + nd * 16 + l15;
                    Ab[row * EMB + col] = f2bf(o_acc[hh][nd][r] * inv_l[r]);
                }
        }
    }
}

extern "C" void kernel_launch(void* const* d_in, const int* in_sizes, int n_in,
                              void* d_out, int out_size, void* d_ws, size_t ws_size,
                              hipStream_t stream) {
    const float* x  = (const float*)d_in[0];
    const float* Wq = (const float*)d_in[1];
    const float* Wk = (const float*)d_in[2];
    const float* Wv = (const float*)d_in[3];
    const float* Wo = (const float*)d_in[4];
    const float* bo = (const float*)d_in[5];
    float* out = (float*)d_out;

    ushort* ws = (ushort*)d_ws;
    ushort* Xb    = ws;                              // [8192][2048]
    ushort* Wq_t  = Xb    + (size_t)MROWS * EMB;     // [2048][2048]
    ushort* Wkv_t = Wq_t  + (size_t)EMB * EMB;       // [256][2048]
    ushort* Wo_t  = Wkv_t + (size_t)256 * EMB;       // [2048][2048]
    ushort* Qb    = Wo_t  + (size_t)EMB * EMB;       // [8192][2048]
    ushort* Kb    = Qb    + (size_t)MROWS * EMB;     // [8192][128]
    ushort* Vg    = Kb    + (size_t)MROWS * HDIM;    // V^T [128][8192]
    ushort* Ab    = Vg    + (size_t)HDIM * MROWS;    // [8192][2048]

    cast_bf16_kernel<<<dim3(MROWS * EMB / 1024), 256, 0, stream>>>(x, Xb, MROWS * EMB);
    transpose_cast_kernel<<<dim3(EMB / 32, EMB / 32), dim3(32, 8), 0, stream>>>(Wq, Wq_t, EMB, EMB);
    transpose_cast_kernel<<<dim3(HDIM / 32, EMB / 32), dim3(32, 8), 0, stream>>>(Wk, Wkv_t, EMB, HDIM);
    transpose_cast_kernel<<<dim3(HDIM / 32, EMB / 32), dim3(32, 8), 0, stream>>>(Wv, Wkv_t + (size_t)HDIM * EMB, EMB, HDIM);
    transpose_cast_kernel<<<dim3(EMB / 32, EMB / 32), dim3(32, 8), 0, stream>>>(Wo, Wo_t, EMB, EMB);

    gemm_bt_kernel<0><<<dim3(EMB / 128, MROWS / 128), 256, 0, stream>>>(Xb, Wq_t, Qb, nullptr, nullptr, MROWS, EMB, EMB);
    gemm_bt_kernel<2><<<dim3(2, MROWS / 128), 256, 0, stream>>>(Xb, Wkv_t, Kb, Vg, nullptr, MROWS, 256, EMB);
    mqa_attn_kernel<<<dim3(QTILES / 2, NHEADS / 2, BATCH), 256, 0, stream>>>(Qb, Kb, Vg, Ab);
    gemm_bt_kernel<1><<<dim3(EMB / 128, MROWS / 128), 256, 0, stream>>>(Ab, Wo_t, out, nullptr, bo, MROWS, EMB, EMB);
}

// Round 2
// 557.065 us; speedup vs baseline: 1.0413x; 1.0365x over previous
//
#include <hip/hip_runtime.h>
#include <stdint.h>

typedef __attribute__((ext_vector_type(8))) short short8;
typedef __attribute__((ext_vector_type(4))) float floatx4;

#define TLEN 2048
#define BATCH 4
#define EMB 2048
#define NHEADS 16
#define HDIM 128
#define MROWS (BATCH * TLEN) /* 8192 */
#define QTILES (TLEN / 64)   /* 32 */

__device__ __forceinline__ ushort f2bf(float f) {
    union { float f; uint32_t u; } v; v.f = f;
    uint32_t u = v.u;
    return (ushort)((u + 0x7fffu + ((u >> 16) & 1u)) >> 16);
}

__device__ __forceinline__ uint32_t cvt_pk_bf16(float a, float b) {
    uint32_t r;
    asm volatile("v_cvt_pk_bf16_f32 %0, %1, %2" : "=v"(r) : "v"(a), "v"(b));
    return r;
}

__device__ __forceinline__ void async_copy16(const ushort* g, ushort* l) {
    __builtin_amdgcn_global_load_lds(
        (const __attribute__((address_space(1))) uint32_t*)g,
        (__attribute__((address_space(3))) uint32_t*)l, 16, 0, 0);
}

// ---------------- cast fp32 -> bf16 ----------------
__global__ __launch_bounds__(256) void cast_bf16_kernel(const float* __restrict__ in,
                                                        ushort* __restrict__ out, int n) {
    int i = (blockIdx.x * 256 + threadIdx.x) * 4;
    if (i >= n) return;
    float4 f = *(const float4*)(in + i);
    ushort4 o;
    o.x = f2bf(f.x); o.y = f2bf(f.y); o.z = f2bf(f.z); o.w = f2bf(f.w);
    *(ushort4*)(out + i) = o;
}

// ---------------- transpose + cast: fp32 [R][Cc] -> bf16 [Cc][R] ----------------
__global__ void transpose_cast_kernel(const float* __restrict__ in, ushort* __restrict__ out,
                                      int R, int Cc) {
    __shared__ float tile[32][33];
    int x = blockIdx.x * 32 + threadIdx.x;
    int y0 = blockIdx.y * 32;
#pragma unroll
    for (int i = 0; i < 4; i++) {
        int y = y0 + threadIdx.y + i * 8;
        tile[threadIdx.y + i * 8][threadIdx.x] = in[(size_t)y * Cc + x];
    }
    __syncthreads();
    int xo = y0 + threadIdx.x;
#pragma unroll
    for (int i = 0; i < 4; i++) {
        int yo = blockIdx.x * 32 + threadIdx.y + i * 8;
        out[(size_t)yo * R + xo] = f2bf(tile[threadIdx.x][threadIdx.y + i * 8]);
    }
}

// ---------------- bf16 MFMA GEMM (m97 structure): C = A[M,K] * Bt[N,K]^T ----------------
template <int MODE>
__global__ __launch_bounds__(256) void gemm_bt_kernel(const ushort* __restrict__ A,
                                                      const ushort* __restrict__ Bt,
                                                      void* __restrict__ Cp,
                                                      void* __restrict__ Cp2,
                                                      const float* __restrict__ bias,
                                                      int M, int N, int K) {
    __shared__ ushort As[128 * 64];
    __shared__ ushort Bs[128 * 64];
    int tid = threadIdx.x;
    int wid = tid >> 6, lane = tid & 63;
    int quad = lane >> 4, l15 = lane & 15;
    int m0 = blockIdx.y * 128;
    int n0 = blockIdx.x * 128;
    int rm = (wid >> 1) * 64;
    int cn = (wid & 1) * 64;
    int grow = lane >> 3;       // 0..7
    int gcol = (lane & 7) * 8;  // 0..56

    floatx4 acc[4][4];
#pragma unroll
    for (int i = 0; i < 4; i++)
#pragma unroll
        for (int j = 0; j < 4; j++)
#pragma unroll
            for (int r = 0; r < 4; r++) acc[i][j][r] = 0.f;

    for (int kk = 0; kk < K; kk += 64) {
#pragma unroll
        for (int c = 0; c < 4; c++) {
            int chunk = wid * 4 + c;              // 0..15, wave-uniform
            int row = chunk * 8 + grow;
            async_copy16(A + (size_t)(m0 + row) * K + kk + gcol, &As[chunk * 512]);
            async_copy16(Bt + (size_t)(n0 + row) * K + kk + gcol, &Bs[chunk * 512]);
        }
        __syncthreads();
#pragma unroll
        for (int ks = 0; ks < 64; ks += 32) {
            short8 af[4], bf[4];
#pragma unroll
            for (int i = 0; i < 4; i++)
                af[i] = *(const short8*)(&As[(rm + i * 16 + l15) * 64 + ks + quad * 8]);
#pragma unroll
            for (int j = 0; j < 4; j++)
                bf[j] = *(const short8*)(&Bs[(cn + j * 16 + l15) * 64 + ks + quad * 8]);
#pragma unroll
            for (int i = 0; i < 4; i++)
#pragma unroll
                for (int j = 0; j < 4; j++)
                    acc[i][j] = __builtin_amdgcn_mfma_f32_16x16x32_bf16(af[i], bf[j], acc[i][j], 0, 0, 0);
        }
        __syncthreads();
    }
#pragma unroll
    for (int i = 0; i < 4; i++)
#pragma unroll
        for (int j = 0; j < 4; j++) {
            if (MODE == 2 && n0 != 0) {
                int d = cn + j * 16 + l15;
                int row = m0 + rm + i * 16 + quad * 4;
                ushort4 o;
                o.x = f2bf(acc[i][j][0]); o.y = f2bf(acc[i][j][1]);
                o.z = f2bf(acc[i][j][2]); o.w = f2bf(acc[i][j][3]);
                *(ushort4*)((ushort*)Cp2 + (size_t)d * M + row) = o;
            } else {
#pragma unroll
                for (int r = 0; r < 4; r++) {
                    int row = m0 + rm + i * 16 + quad * 4 + r;
                    int col = n0 + cn + j * 16 + l15;
                    float v = acc[i][j][r];
                    if (MODE == 0) {
                        ((ushort*)Cp)[(size_t)row * N + col] = f2bf(v);
                    } else if (MODE == 1) {
                        ((float*)Cp)[(size_t)row * N + col] = v + bias[col];
                    } else {
                        ((ushort*)Cp)[(size_t)row * HDIM + col] = f2bf(v);
                    }
                }
            }
        }
}

// ---------------- flash MQA attention: 1 q-tile/block, 2 heads, P in registers ----------------
// grid: (QTILES, H/2, B) = 1024 blocks -> 4 blocks/CU resident (LDS 32KB, VGPR<=128).
// K/V staged via swizzled global_load_lds (linear LDS + pre-swizzled source, col ^= (row&7)<<3).
// Swapped QK^T leaves lane (quad,l15) with S^T[key=16j+4q+r][qrow=l15]; the PV A-frag needs
// P[l15][kt*32+8q+t]. That redistribution is pure cross-quad same-l15:
//   permlane32_swap + permlane16_swap per dword-pair assembles the frag exactly. No Ps LDS.
__global__ __launch_bounds__(256, 4) void mqa_attn_kernel(const ushort* __restrict__ Qb,
                                                          const ushort* __restrict__ Kb,
                                                          const ushort* __restrict__ Vg,
                                                          ushort* __restrict__ Ab) {
    __shared__ ushort Ks[64 * 128];   // [key][d], XOR-swizzled cols
    __shared__ ushort Vs[128 * 64];   // V^T [d][key], XOR-swizzled cols
    int tid = threadIdx.x;
    int wid = tid >> 6, lane = tid & 63;
    int quad = lane >> 4, l15 = lane & 15;
    int h0 = blockIdx.y * 2, b = blockIdx.z;
    int qt = (QTILES - 1) - blockIdx.x;   // longest blocks dispatched first
    const float scale2 = 0.08838834764831845f * 1.4426950408889634f; // 1/sqrt(128)*log2(e)
    const ushort* kbase = Kb + (size_t)b * TLEN * HDIM;
    const ushort* vbase = Vg + (size_t)b * TLEN;
    size_t qrowbase = (size_t)b * TLEN + qt * 64;

    // Q fragments in registers (reused across all jt)
    short8 aq[2][4];
#pragma unroll
    for (int hh = 0; hh < 2; hh++) {
        const ushort* qp = Qb + (qrowbase + wid * 16 + l15) * EMB + (h0 + hh) * HDIM + quad * 8;
#pragma unroll
        for (int kd = 0; kd < 4; kd++) aq[hh][kd] = *(const short8*)(qp + kd * 32);
    }

    float lsum[2] = {0.f, 0.f};
    floatx4 o_acc[2][8];
#pragma unroll
    for (int hh = 0; hh < 2; hh++)
#pragma unroll
        for (int nd = 0; nd < 8; nd++)
#pragma unroll
            for (int r = 0; r < 4; r++) o_acc[hh][nd][r] = 0.f;

    int rowloc = wid * 16 + l15;
    int swz = (l15 & 7) << 3;

#pragma unroll 1
    for (int jt = 0; jt <= qt; ++jt) {
        // ---- stage K/V tile via global_load_lds, swizzled source ----
#pragma unroll
        for (int i = 0; i < 4; i++) {
            int c = wid * 4 + i;                             // chunk 0..15 (1KB each)
            int kr = c * 4 + (lane >> 4);                    // K row in tile 0..63
            int kc = ((lane & 15) * 8) ^ ((kr & 7) << 3);    // swizzled ushort col
            async_copy16(kbase + (size_t)(jt * 64 + kr) * HDIM + kc, &Ks[c * 512]);
            int vd = c * 8 + (lane >> 3);                    // V d-row 0..127
            int vc = ((lane & 7) * 8) ^ ((lane >> 3) << 3);  // swizzled ushort col (vd&7 == lane>>3)
            async_copy16(vbase + (size_t)vd * MROWS + jt * 64 + vc, &Vs[c * 512]);
        }
        __syncthreads();   // drains vmcnt: all gload_lds landed

        bool diag = (jt == qt);
#pragma unroll
        for (int jp = 0; jp < 2; jp++) {     // key half: j in {2jp, 2jp+1}, PV chunk kt=jp
            uint32_t XA[2][2], XB[2][2];     // [hh][jj] packed bf16 pairs
#pragma unroll
            for (int jj = 0; jj < 2; jj++) {
                int j = jp * 2 + jj;
                floatx4 s0, s1;
#pragma unroll
                for (int r = 0; r < 4; r++) { s0[r] = 0.f; s1[r] = 0.f; }
                __builtin_amdgcn_s_setprio(1);
#pragma unroll
                for (int kd = 0; kd < 4; kd++) {
                    short8 ak = *(const short8*)(&Ks[(j * 16 + l15) * 128 + ((kd * 32 + quad * 8) ^ swz)]);
                    s0 = __builtin_amdgcn_mfma_f32_16x16x32_bf16(ak, aq[0][kd], s0, 0, 0, 0);
                    s1 = __builtin_amdgcn_mfma_f32_16x16x32_bf16(ak, aq[1][kd], s1, 0, 0, 0);
                }
                __builtin_amdgcn_s_setprio(0);
                // softmax (fixed-max): e = exp2(s*scale2), causal mask, per-lane row partials
                float e0[4], e1[4];
#pragma unroll
                for (int r = 0; r < 4; r++) {
                    int key = j * 16 + quad * 4 + r;
                    float v0 = exp2f(s0[r] * scale2);
                    float v1 = exp2f(s1[r] * scale2);
                    if (diag && key > rowloc) { v0 = 0.f; v1 = 0.f; }
                    e0[r] = v0; e1[r] = v1;
                    lsum[0] += v0; lsum[1] += v1;
                }
                XA[0][jj] = cvt_pk_bf16(e0[0], e0[1]); XB[0][jj] = cvt_pk_bf16(e0[2], e0[3]);
                XA[1][jj] = cvt_pk_bf16(e1[0], e1[1]); XB[1][jj] = cvt_pk_bf16(e1[2], e1[3]);
            }
            // ---- cross-quad redistribution -> PV A-fragments (in-register) ----
            short8 pf[2];
#pragma unroll
            for (int hh = 0; hh < 2; hh++) {
                uint32_t xA = XA[hh][0], yA = XA[hh][1];
                uint32_t xB = XB[hh][0], yB = XB[hh][1];
                asm volatile("v_permlane32_swap_b32 %0, %1" : "+v"(xA), "+v"(yA));
                asm volatile("v_permlane16_swap_b32 %0, %1" : "+v"(xA), "+v"(yA));
                asm volatile("v_permlane32_swap_b32 %0, %1" : "+v"(xB), "+v"(yB));
                asm volatile("v_permlane16_swap_b32 %0, %1" : "+v"(xB), "+v"(yB));
                union { uint32_t u[4]; short8 s; } fu;
                fu.u[0] = xA; fu.u[1] = xB; fu.u[2] = yA; fu.u[3] = yB;
                pf[hh] = fu.s;
            }
            // ---- O += P V for this 32-key chunk ----
            __builtin_amdgcn_s_setprio(1);
#pragma unroll
            for (int nd = 0; nd < 8; nd++) {
                short8 vf = *(const short8*)(&Vs[(nd * 16 + l15) * 64 + ((jp * 32 + quad * 8) ^ swz)]);
                o_acc[0][nd] = __builtin_amdgcn_mfma_f32_16x16x32_bf16(pf[0], vf, o_acc[0][nd], 0, 0, 0);
                o_acc[1][nd] = __builtin_amdgcn_mfma_f32_16x16x32_bf16(pf[1], vf, o_acc[1][nd], 0, 0, 0);
            }
            __builtin_amdgcn_s_setprio(0);
        }
        __syncthreads();   // all reads done before next tile overwrites LDS
    }

    // row sums: lane holds partial for q-row l15; reduce across quads, then gather
    // the 4 rows (quad*4+r) this lane's o_acc covers via width-16 shfl.
#pragma unroll
    for (int hh = 0; hh < 2; hh++) {
        float ls = lsum[hh];
        ls += __shfl_xor(ls, 16);
        ls += __shfl_xor(ls, 32);
        float inv_l[4];
#pragma unroll
        for (int r = 0; r < 4; r++) inv_l[r] = 1.f / __shfl(ls, quad * 4 + r, 16);
#pragma unroll
        for (int nd = 0; nd < 8; nd++)
#pragma unroll
            for (int r = 0; r < 4; r++) {
                size_t row = qrowbase + wid * 16 + quad * 4 + r;
                int col = (h0 + hh) * HDIM + nd * 16 + l15;
                Ab[row * EMB + col] = f2bf(o_acc[hh][nd][r] * inv_l[r]);
            }
    }
}

extern "C" void kernel_launch(void* const* d_in, const int* in_sizes, int n_in,
                              void* d_out, int out_size, void* d_ws, size_t ws_size,
                              hipStream_t stream) {
    const float* x  = (const float*)d_in[0];
    const float* Wq = (const float*)d_in[1];
    const float* Wk = (const float*)d_in[2];
    const float* Wv = (const float*)d_in[3];
    const float* Wo = (const float*)d_in[4];
    const float* bo = (const float*)d_in[5];
    float* out = (float*)d_out;

    ushort* ws = (ushort*)d_ws;
    ushort* Xb    = ws;                              // [8192][2048]
    ushort* Wq_t  = Xb    + (size_t)MROWS * EMB;     // [2048][2048]
    ushort* Wkv_t = Wq_t  + (size_t)EMB * EMB;       // [256][2048]
    ushort* Wo_t  = Wkv_t + (size_t)256 * EMB;       // [2048][2048]
    ushort* Qb    = Wo_t  + (size_t)EMB * EMB;       // [8192][2048]
    ushort* Kb    = Qb    + (size_t)MROWS * EMB;     // [8192][128]
    ushort* Vg    = Kb    + (size_t)MROWS * HDIM;    // V^T [128][8192]
    ushort* Ab    = Vg    + (size_t)HDIM * MROWS;    // [8192][2048]

    cast_bf16_kernel<<<dim3(MROWS * EMB / 1024), 256, 0, stream>>>(x, Xb, MROWS * EMB);
    transpose_cast_kernel<<<dim3(EMB / 32, EMB / 32), dim3(32, 8), 0, stream>>>(Wq, Wq_t, EMB, EMB);
    transpose_cast_kernel<<<dim3(HDIM / 32, EMB / 32), dim3(32, 8), 0, stream>>>(Wk, Wkv_t, EMB, HDIM);
    transpose_cast_kernel<<<dim3(HDIM / 32, EMB / 32), dim3(32, 8), 0, stream>>>(Wv, Wkv_t + (size_t)HDIM * EMB, EMB, HDIM);
    transpose_cast_kernel<<<dim3(EMB / 32, EMB / 32), dim3(32, 8), 0, stream>>>(Wo, Wo_t, EMB, EMB);

    gemm_bt_kernel<0><<<dim3(EMB / 128, MROWS / 128), 256, 0, stream>>>(Xb, Wq_t, Qb, nullptr, nullptr, MROWS, EMB, EMB);
    gemm_bt_kernel<2><<<dim3(2, MROWS / 128), 256, 0, stream>>>(Xb, Wkv_t, Kb, Vg, nullptr, MROWS, 256, EMB);
    mqa_attn_kernel<<<dim3(QTILES, NHEADS / 2, BATCH), 256, 0, stream>>>(Qb, Kb, Vg, Ab);
    gemm_bt_kernel<1><<<dim3(EMB / 128, MROWS / 128), 256, 0, stream>>>(Ab, Wo_t, out, nullptr, bo, MROWS, EMB, EMB);
}